// Round 1
// baseline (443.787 us; speedup 1.0000x reference)
//
#include <hip/hip_runtime.h>

#define D_CH   1024
#define L_SEQ  8192
#define TWO_PI 6.28318530717958647692f
#define W_N    3.8349519697141029e-4f   /* 2*pi/16384 */

// ---------------- bf16 pack/unpack (manual RNE, no API dependence) -------
__device__ __forceinline__ unsigned f2bf(float v){
  union { float f; unsigned u; } x; x.f = v;
  unsigned r = x.u + 0x7fffu + ((x.u >> 16) & 1u);
  return r >> 16;
}
__device__ __forceinline__ float bf2f(unsigned v){
  union { float f; unsigned u; } x; x.u = v << 16;
  return x.f;
}
__device__ __forceinline__ unsigned packc(float r, float i){
  return f2bf(r) | (f2bf(i) << 16);
}

__device__ __host__ constexpr int bitrev6(int j){
  return ((j&1)<<5)|((j&2)<<3)|((j&4)<<1)|((j&8)>>1)|((j&16)>>3)|((j&32)>>5);
}

// DIF 64-pt DFT, natural input, slot j holds X[bitrev6(j)].
// SGN=+1: X[k]=sum x[n] e^{-2pi i nk/64}; SGN=-1: positive exponent.
template<int SGN>
__device__ __forceinline__ void dft64_dif(float* xr, float* xi, const float2* W){
#pragma unroll
  for (int len = 64; len >= 2; len >>= 1){
    const int half = len >> 1;
    const int tstep = 128 / len;           // twiddle e^{-2pi i j/len} = W[j*tstep]
#pragma unroll
    for (int st = 0; st < 64; st += len){
#pragma unroll
      for (int j = 0; j < half; j++){
        const float2 w = W[j * tstep];
        const float wr = w.x;
        const float wi = (SGN > 0) ? w.y : -w.y;
        const int a = st + j, b = a + half;
        const float ur = xr[a], ui = xi[a];
        const float vr = xr[b], vi = xi[b];
        xr[a] = ur + vr; xi[a] = ui + vi;
        const float dr = ur - vr, di = ui - vi;
        xr[b] = dr * wr - di * wi;
        xi[b] = dr * wi + di * wr;
      }
    }
  }
}

// DIT 64-pt: slot j = V[bitrev6(j)] input, natural output,
// out[p] = sum_m V[m] e^{+2pi i p m / 64}
__device__ __forceinline__ void idft64_dit(float* xr, float* xi, const float2* W){
#pragma unroll
  for (int len = 2; len <= 64; len <<= 1){
    const int half = len >> 1;
    const int tstep = 128 / len;
#pragma unroll
    for (int st = 0; st < 64; st += len){
#pragma unroll
      for (int j = 0; j < half; j++){
        const float2 w = W[j * tstep];
        const float wr = w.x, wi = -w.y;   // conj -> e^{+i...}
        const int a = st + j, b = a + half;
        const float br = xr[b], bi = xi[b];
        const float vr = br * wr - bi * wi;
        const float vi = br * wi + bi * wr;
        const float ur = xr[a], ui = xi[a];
        xr[a] = ur + vr; xi[a] = ui + vi;
        xr[b] = ur - vr; xi[b] = ui - vi;
      }
    }
  }
}

__device__ __forceinline__ void init_w128(float2* W){
  const int tid = threadIdx.x;
  if (tid < 128){
    float s, c;
    __sincosf(-TWO_PI * (float)tid * (1.0f/128.0f), &s, &c);
    W[tid] = make_float2(c, s);            // e^{-2pi i tid/128}
  }
  __syncthreads();
}

// ---------------------------------------------------------------------------
// K1: forward step1. n = n2 + 128*n1 (n1 zero for n1>=64 due to zero-pad).
// A[k1,n2] = e^{-2pi i k1 n2/16384} * sum_{n1<64} z[n1] e^{-2pi i n1 k1/128}
// wave0 -> even k1 (plain DFT64), wave1 -> odd k1 (pre-twiddle W128^n1).
// mode 0: z = x[0] + i x[1]; mode 1: h (imag 0).
// ---------------------------------------------------------------------------
__global__ __launch_bounds__(128, 2)
void k1_step1(const float* __restrict__ x, const float* __restrict__ h,
              unsigned* __restrict__ Az, unsigned* __restrict__ Ah){
  __shared__ float2 W[128];
  init_w128(W);
  const int n2   = blockIdx.x;           // [0,128)
  const int dg   = blockIdx.y;           // [0,16)
  const int mode = blockIdx.z;           // 0 = z, 1 = h
  const int wave = threadIdx.x >> 6;
  const int lane = threadIdx.x & 63;
  const int d    = dg * 64 + lane;

  float xr[64], xi[64];
  if (mode == 0){
    const float* x0 = x;
    const float* x1 = x + (size_t)L_SEQ * D_CH;
#pragma unroll
    for (int n1 = 0; n1 < 64; n1++){
      const size_t off = (size_t)(n2 + 128*n1) * D_CH + d;
      xr[n1] = x0[off];
      xi[n1] = x1[off];
    }
  } else {
#pragma unroll
    for (int n1 = 0; n1 < 64; n1++){
      xr[n1] = h[(size_t)(n2 + 128*n1) * D_CH + d];
      xi[n1] = 0.0f;
    }
  }
  if (wave){
#pragma unroll
    for (int n1 = 0; n1 < 64; n1++){
      const float2 w = W[n1];            // e^{-2pi i n1/128}
      const float r  = xr[n1]*w.x - xi[n1]*w.y;
      const float im = xr[n1]*w.y + xi[n1]*w.x;
      xr[n1] = r; xi[n1] = im;
    }
  }
  dft64_dif<1>(xr, xi, W);
  unsigned* __restrict__ A = mode ? Ah : Az;
#pragma unroll
  for (int j = 0; j < 64; j++){
    const int k1 = 2*bitrev6(j) + wave;
    float s, c;
    __sincosf(-W_N * (float)(k1 * n2), &s, &c);
    const float ar = xr[j]*c - xi[j]*s;
    const float ai = xr[j]*s + xi[j]*c;
    A[((size_t)k1*128 + n2) * D_CH + d] = packc(ar, ai);
  }
}

// ---------------------------------------------------------------------------
// K2h: forward step2 for h, in place: A_h[k1,n2] -> Hspec[k1,k2].
// 128-pt DFT over n2 via parity fold: wave0 even k2 (a+b), wave1 odd k2
// ((a-b)*W128^n2). Barrier between (loads of whole slice) and (stores).
// ---------------------------------------------------------------------------
__global__ __launch_bounds__(128, 2)
void k2_h(unsigned* __restrict__ Ah){
  __shared__ float2 W[128];
  init_w128(W);
  const int k1 = blockIdx.x, dg = blockIdx.y;
  const int wave = threadIdx.x >> 6, lane = threadIdx.x & 63;
  const int d = dg*64 + lane;
  const size_t base = (size_t)k1 * 128 * D_CH + d;

  float xr[64], xi[64];
#pragma unroll
  for (int n = 0; n < 64; n++){
    const unsigned pa = Ah[base + (size_t)n * D_CH];
    const unsigned pb = Ah[base + (size_t)(n+64) * D_CH];
    const float ar = bf2f(pa & 0xffffu), ai = bf2f(pa >> 16);
    const float br = bf2f(pb & 0xffffu), bi = bf2f(pb >> 16);
    if (wave == 0){ xr[n] = ar + br; xi[n] = ai + bi; }
    else {
      const float dr = ar - br, di = ai - bi;
      const float2 w = W[n];
      xr[n] = dr*w.x - di*w.y;
      xi[n] = dr*w.y + di*w.x;
    }
  }
  __syncthreads();   // all loads of the slice complete before in-place stores
  dft64_dif<1>(xr, xi, W);
#pragma unroll
  for (int j = 0; j < 64; j++){
    const int k2 = 2*bitrev6(j) + wave;
    Ah[base + (size_t)k2 * D_CH] = packc(xr[j], xi[j]);
  }
}

// ---------------------------------------------------------------------------
// K2z: forward step2 for z + pointwise (Z*H/16384) + inverse step1 (over k2),
// in place over A_z. wave0 stores BA[p] at i2=p, wave1 stores BB[p] at 64+p.
// B[k1,m2] = BA[k1,m2&63] + e^{+2pi i m2/128} BB[k1,m2&63] (combined in K3).
// ---------------------------------------------------------------------------
__global__ __launch_bounds__(128, 2)
void k2_z(unsigned* __restrict__ Az, const unsigned* __restrict__ Hs){
  __shared__ float2 W[128];
  init_w128(W);
  const int k1 = blockIdx.x, dg = blockIdx.y;
  const int wave = threadIdx.x >> 6, lane = threadIdx.x & 63;
  const int d = dg*64 + lane;
  const size_t base = (size_t)k1 * 128 * D_CH + d;

  float xr[64], xi[64];
#pragma unroll
  for (int n = 0; n < 64; n++){
    const unsigned pa = Az[base + (size_t)n * D_CH];
    const unsigned pb = Az[base + (size_t)(n+64) * D_CH];
    const float ar = bf2f(pa & 0xffffu), ai = bf2f(pa >> 16);
    const float br = bf2f(pb & 0xffffu), bi = bf2f(pb >> 16);
    if (wave == 0){ xr[n] = ar + br; xi[n] = ai + bi; }
    else {
      const float dr = ar - br, di = ai - bi;
      const float2 w = W[n];
      xr[n] = dr*w.x - di*w.y;
      xi[n] = dr*w.y + di*w.x;
    }
  }
  __syncthreads();
  dft64_dif<1>(xr, xi, W);                 // slot j: Z at k2 = 2*bitrev6(j)+wave
  const float sc = 1.0f / 16384.0f;
#pragma unroll
  for (int j = 0; j < 64; j++){
    const int k2 = 2*bitrev6(j) + wave;
    const unsigned ph = Hs[base + (size_t)k2 * D_CH];
    const float hr = bf2f(ph & 0xffffu), hi = bf2f(ph >> 16);
    const float zr = xr[j], zi = xi[j];
    xr[j] = (zr*hr - zi*hi) * sc;
    xi[j] = (zr*hi + zi*hr) * sc;
  }
  idft64_dit(xr, xi, W);                   // natural p output
#pragma unroll
  for (int p = 0; p < 64; p++){
    Az[base + (size_t)(wave*64 + p) * D_CH] = packc(xr[p], xi[p]);
  }
}

// ---------------------------------------------------------------------------
// K3: inverse step2 over k1 for one m2 slice. Combine BA/BB into B[k1,m2],
// pre-twiddle e^{+2pi i m2 k1/16384}, then parity-split inverse DFT over k1:
// wave0 (even k1) -> P[m1], wave1 (odd k1) -> Q[m1], m1 in [0,64) (= kept half).
// ---------------------------------------------------------------------------
__global__ __launch_bounds__(128, 2)
void k3_inv2(const unsigned* __restrict__ Bz, unsigned* __restrict__ PQ){
  __shared__ float2 W[128];
  init_w128(W);
  const int m2 = blockIdx.x, dg = blockIdx.y;
  const int wave = threadIdx.x >> 6, lane = threadIdx.x & 63;
  const int d = dg*64 + lane;
  const int p2 = m2 & 63;
  const float2 wm = W[m2];
  const float tr = wm.x, ti = -wm.y;       // e^{+2pi i m2/128}

  float xr[64], xi[64];
#pragma unroll
  for (int q = 0; q < 64; q++){
    const int k1 = 2*q + wave;
    const size_t rowbase = (size_t)k1 * 128 * D_CH + d;
    const unsigned pa = Bz[rowbase + (size_t)p2 * D_CH];          // BA
    const unsigned pb = Bz[rowbase + (size_t)(64 + p2) * D_CH];   // BB
    const float ar = bf2f(pa & 0xffffu), ai = bf2f(pa >> 16);
    const float br = bf2f(pb & 0xffffu), bi = bf2f(pb >> 16);
    const float cr = ar + (br*tr - bi*ti);
    const float ci = ai + (br*ti + bi*tr);
    float s, c;
    __sincosf(W_N * (float)(m2 * k1), &s, &c);                    // +2pi m2 k1/N
    xr[q] = cr*c - ci*s;
    xi[q] = cr*s + ci*c;
  }
  dft64_dif<-1>(xr, xi, W);                // out[j] = sum_q C[q] e^{+2pi i q*bitrev6(j)/64}
#pragma unroll
  for (int j = 0; j < 64; j++){
    const int m1 = bitrev6(j);
    PQ[((size_t)m2*128 + wave*64 + m1) * D_CH + d] = packc(xr[j], xi[j]);
  }
}

// ---------------------------------------------------------------------------
// K4: w[m1,m2] = P + e^{+2pi i m1/128} Q; t = m2 + 128*m1 < 8192;
// y[0,t,d] = Re(w)+bias[d]; y[1,t,d] = Im(w)+bias[d].
// ---------------------------------------------------------------------------
__global__ __launch_bounds__(256)
void k4_final(const unsigned* __restrict__ PQ, const float* __restrict__ bias,
              float* __restrict__ out){
  const int i  = blockIdx.x * 256 + threadIdx.x;   // [0, 8192*1024)
  const int d  = i & (D_CH - 1);
  const int t  = i >> 10;
  const int m2 = t & 127;
  const int m1 = t >> 7;
  const unsigned pp = PQ[((size_t)m2*128 + m1) * D_CH + d];
  const unsigned pq = PQ[((size_t)m2*128 + 64 + m1) * D_CH + d];
  float s, c;
  __sincosf(TWO_PI * (float)m1 * (1.0f/128.0f), &s, &c);
  const float pr = bf2f(pp & 0xffffu), pi = bf2f(pp >> 16);
  const float qr = bf2f(pq & 0xffffu), qi = bf2f(pq >> 16);
  const float wr = pr + (qr*c - qi*s);
  const float wi = pi + (qr*s + qi*c);
  const float bv = bias[d];
  out[i] = wr + bv;
  out[(size_t)L_SEQ * D_CH + i] = wi + bv;
}

// ---------------------------------------------------------------------------
extern "C" void kernel_launch(void* const* d_in, const int* in_sizes, int n_in,
                              void* d_out, int out_size, void* d_ws, size_t ws_size,
                              hipStream_t stream){
  (void)in_sizes; (void)n_in; (void)out_size;
  const float* x    = (const float*)d_in[0];
  const float* h    = (const float*)d_in[1];
  const float* bias = (const float*)d_in[2];
  float* out = (float*)d_out;

  const size_t REGION = (size_t)128 * 128 * D_CH * sizeof(unsigned); // 64 MiB
  unsigned *r1, *r2;
  if (ws_size >= 2 * REGION){
    r1 = (unsigned*)d_ws;                       // A_z -> BA/BB
    r2 = (unsigned*)((char*)d_ws + REGION);     // A_h -> Hspec -> P/Q
  } else {
    r1 = (unsigned*)d_out;  // exact 64 MiB fit; dead before K4 writes y
    r2 = (unsigned*)d_ws;   // requires ws_size >= 64 MiB
  }

  const dim3 blk(128, 1, 1);
  hipLaunchKernelGGL(k1_step1, dim3(128,16,2), blk, 0, stream, x, h, r1, r2);
  hipLaunchKernelGGL(k2_h,     dim3(128,16,1), blk, 0, stream, r2);
  hipLaunchKernelGGL(k2_z,     dim3(128,16,1), blk, 0, stream, r1, r2);
  hipLaunchKernelGGL(k3_inv2,  dim3(128,16,1), blk, 0, stream, r1, r2);
  hipLaunchKernelGGL(k4_final, dim3(32768,1,1), dim3(256,1,1), 0, stream, r2, bias, out);
}

// Round 2
// 260.969 us; speedup vs baseline: 1.7005x; 1.7005x over previous
//
#include <hip/hip_runtime.h>

#define D_CH   1024
#define L_SEQ  8192
#define TWO_PI 6.28318530717958647692f
#define W_N    3.8349519697141029e-4f   /* 2*pi/16384 */
#define W128A  4.90873852123405e-2f     /* 2*pi/128 */

// ---------------- bf16 pack/unpack (manual RNE) --------------------------
__device__ __forceinline__ unsigned f2bf(float v){
  union { float f; unsigned u; } x; x.f = v;
  unsigned r = x.u + 0x7fffu + ((x.u >> 16) & 1u);
  return r >> 16;
}
__device__ __forceinline__ float bf2f(unsigned v){
  union { float f; unsigned u; } x; x.u = v << 16;
  return x.f;
}
__device__ __forceinline__ unsigned packc(float r, float i){
  return f2bf(r) | (f2bf(i) << 16);
}
__device__ __forceinline__ float2 upk(unsigned u){
  return make_float2(bf2f(u & 0xffffu), bf2f(u >> 16));
}

__device__ __host__ constexpr int bitrev4(int j){
  return ((j&1)<<3)|((j&2)<<1)|((j&4)>>1)|((j&8)>>3);
}
__device__ __host__ constexpr int bitrev3(int j){
  return ((j&1)<<2)|(j&2)|((j&4)>>2);
}

// 16-pt DIF DFT, natural in; slot j holds X[bitrev4(j)].
// SGN=+1: e^{-i}, SGN=-1: e^{+i} (unnormalized).
template<int SGN>
__device__ __forceinline__ void dft16(float2* x){
  const float TC[8] = {1.f, 0.9238795325f, 0.7071067812f, 0.3826834324f,
                       0.f, -0.3826834324f, -0.7071067812f, -0.9238795325f};
  const float TS[8] = {0.f, -0.3826834324f, -0.7071067812f, -0.9238795325f,
                       -1.f, -0.9238795325f, -0.7071067812f, -0.3826834324f};
#pragma unroll
  for (int len = 16; len >= 2; len >>= 1){
    const int half = len >> 1, tstep = 16 / len;
#pragma unroll
    for (int st = 0; st < 16; st += len){
#pragma unroll
      for (int j = 0; j < half; j++){
        const float wr = TC[j*tstep];
        const float wi = (SGN > 0) ? TS[j*tstep] : -TS[j*tstep];
        const int a = st + j, b = a + half;
        const float ur = x[a].x, ui = x[a].y;
        const float vr = x[b].x, vi = x[b].y;
        x[a].x = ur + vr; x[a].y = ui + vi;
        const float dr = ur - vr, di = ui - vi;
        x[b].x = dr*wr - di*wi;
        x[b].y = dr*wi + di*wr;
      }
    }
  }
}

// 8-pt DIF DFT, natural in; slot j holds X[bitrev3(j)].
template<int SGN>
__device__ __forceinline__ void dft8(float2* x){
  const float TC[4] = {1.f, 0.7071067812f, 0.f, -0.7071067812f};
  const float TS[4] = {0.f, -0.7071067812f, -1.f, -0.7071067812f};
#pragma unroll
  for (int len = 8; len >= 2; len >>= 1){
    const int half = len >> 1, tstep = 8 / len;
#pragma unroll
    for (int st = 0; st < 8; st += len){
#pragma unroll
      for (int j = 0; j < half; j++){
        const float wr = TC[j*tstep];
        const float wi = (SGN > 0) ? TS[j*tstep] : -TS[j*tstep];
        const int a = st + j, b = a + half;
        const float ur = x[a].x, ui = x[a].y;
        const float vr = x[b].x, vi = x[b].y;
        x[a].x = ur + vr; x[a].y = ui + vi;
        const float dr = ur - vr, di = ui - vi;
        x[b].x = dr*wr - di*wi;
        x[b].y = dr*wi + di*wr;
      }
    }
  }
}

// 128-pt DFT cooperatively across 8 p-threads (p = tid>>6), 64 channels
// (lane = tid&63). Entry: v[q] = f[p + 8q], q in [0,16).
// Exit:  v[c*8+t] = F[(2p+c) + 16*bitrev3(t)], c in {0,1}, t in [0,8).
// Uses one 64 KiB LDS transpose (lds = float2[8192]). One internal barrier;
// caller must barrier before reusing lds for anything else.
template<int SGN>
__device__ __forceinline__ void fft128(float2* v, float2* lds, int lane, int p){
  dft16<SGN>(v);                       // slot -> s = bitrev4(slot)
#pragma unroll
  for (int slot = 0; slot < 16; slot++){
    const int s = bitrev4(slot);
    float sn, cs;
    __sincosf(-(float)SGN * W128A * (float)(p*s), &sn, &cs);  // w128^{ps}
    const float2 a = v[slot];
    lds[(p*16 + s)*64 + lane] = make_float2(a.x*cs - a.y*sn, a.x*sn + a.y*cs);
  }
  __syncthreads();
  float2 t8[8];
#pragma unroll
  for (int c = 0; c < 2; c++){
#pragma unroll
    for (int pp = 0; pp < 8; pp++)
      t8[pp] = lds[(pp*16 + 2*p + c)*64 + lane];
    dft8<SGN>(t8);                     // slot t -> r = bitrev3(t)
#pragma unroll
    for (int t = 0; t < 8; t++) v[c*8 + t] = t8[t];
  }
}

// ---------------------------------------------------------------------------
// K1: forward step1 over n1 (64 nonzero of 128, zero-padded).
// A[k1,n2] = w16384^{k1 n2} * DFT128_{n1}(z[n2+128 n1]).
// mode 0: z = x[0] + i x[1]; mode 1: h.
// ---------------------------------------------------------------------------
__global__ __launch_bounds__(512, 4)
void k1_step1(const float* __restrict__ x, const float* __restrict__ h,
              unsigned* __restrict__ Az, unsigned* __restrict__ Ah){
  __shared__ float2 lds[8192];
  const int n2 = blockIdx.x, dg = blockIdx.y, mode = blockIdx.z;
  const int lane = threadIdx.x & 63, p = threadIdx.x >> 6;
  const int d = dg*64 + lane;

  float2 v[16];
  if (mode == 0){
    const float* x0 = x;
    const float* x1 = x + (size_t)L_SEQ * D_CH;
#pragma unroll
    for (int q = 0; q < 8; q++){
      const size_t off = (size_t)(n2 + 128*(p + 8*q)) * D_CH + d;
      v[q] = make_float2(x0[off], x1[off]);
    }
  } else {
#pragma unroll
    for (int q = 0; q < 8; q++){
      const size_t off = (size_t)(n2 + 128*(p + 8*q)) * D_CH + d;
      v[q] = make_float2(h[off], 0.0f);
    }
  }
#pragma unroll
  for (int q = 8; q < 16; q++) v[q] = make_float2(0.f, 0.f);

  fft128<1>(v, lds, lane, p);

  unsigned* __restrict__ A = mode ? Ah : Az;
#pragma unroll
  for (int c = 0; c < 2; c++){
#pragma unroll
    for (int t = 0; t < 8; t++){
      const int k1v = (2*p + c) + 16*bitrev3(t);
      float sn, cs;
      __sincosf(-W_N * (float)(k1v * n2), &sn, &cs);
      const float2 a = v[c*8 + t];
      A[((size_t)k1v*128 + n2)*D_CH + d] =
        packc(a.x*cs - a.y*sn, a.x*sn + a.y*cs);
    }
  }
}

// ---------------------------------------------------------------------------
// K2h: forward step2 over n2 for h, in place: A_h[k1,n2] -> Hspec[k1,k2].
// In-place safe: all global loads consumed before fft128's internal barrier;
// stores issued after it.
// ---------------------------------------------------------------------------
__global__ __launch_bounds__(512, 4)
void k2_h(unsigned* __restrict__ Ah){
  __shared__ float2 lds[8192];
  const int k1 = blockIdx.x, dg = blockIdx.y;
  const int lane = threadIdx.x & 63, p = threadIdx.x >> 6;
  const int d = dg*64 + lane;
  const size_t base = (size_t)k1 * 128 * D_CH + d;

  unsigned raw[16];
#pragma unroll
  for (int q = 0; q < 16; q++)
    raw[q] = Ah[base + (size_t)(p + 8*q) * D_CH];
  float2 v[16];
#pragma unroll
  for (int q = 0; q < 16; q++) v[q] = upk(raw[q]);

  fft128<1>(v, lds, lane, p);

#pragma unroll
  for (int c = 0; c < 2; c++){
#pragma unroll
    for (int t = 0; t < 8; t++){
      const int k2 = (2*p + c) + 16*bitrev3(t);
      const float2 a = v[c*8 + t];
      Ah[base + (size_t)k2 * D_CH] = packc(a.x, a.y);
    }
  }
}

// ---------------------------------------------------------------------------
// K2z: forward step2 for z + pointwise Z*H/16384 + inverse DFT over k2,
// in place on A_z: result b[k1,m2] stored at natural m2.
// ---------------------------------------------------------------------------
__global__ __launch_bounds__(512, 4)
void k2_z(unsigned* __restrict__ Az, const unsigned* __restrict__ Hs){
  __shared__ float2 lds[8192];
  const int k1 = blockIdx.x, dg = blockIdx.y;
  const int lane = threadIdx.x & 63, p = threadIdx.x >> 6;
  const int d = dg*64 + lane;
  const size_t base = (size_t)k1 * 128 * D_CH + d;

  // issue all independent loads up front (MLP)
  unsigned za[16], ha[16];
#pragma unroll
  for (int q = 0; q < 16; q++)
    za[q] = Az[base + (size_t)(p + 8*q) * D_CH];
#pragma unroll
  for (int c = 0; c < 2; c++){
#pragma unroll
    for (int t = 0; t < 8; t++){
      const int k2 = (2*p + c) + 16*bitrev3(t);
      ha[c*8 + t] = Hs[base + (size_t)k2 * D_CH];
    }
  }

  float2 v[16];
#pragma unroll
  for (int q = 0; q < 16; q++) v[q] = upk(za[q]);

  fft128<1>(v, lds, lane, p);          // v[i] = Z at k2 matching ha[i]

  const float sc = 1.0f / 16384.0f;
#pragma unroll
  for (int i = 0; i < 16; i++){
    const float2 hsv = upk(ha[i]);
    const float zr = v[i].x, zi = v[i].y;
    v[i] = make_float2((zr*hsv.x - zi*hsv.y) * sc,
                       (zr*hsv.y + zi*hsv.x) * sc);
  }

  // redistribute: have Y at k2=(2p+c)+16*bitrev3(t); need v[q] = Y[p+8q]
  __syncthreads();                     // protect fft128's lds reads
#pragma unroll
  for (int c = 0; c < 2; c++){
#pragma unroll
    for (int t = 0; t < 8; t++){
      const int k2 = (2*p + c) + 16*bitrev3(t);
      lds[k2*64 + lane] = v[c*8 + t];
    }
  }
  __syncthreads();
#pragma unroll
  for (int q = 0; q < 16; q++) v[q] = lds[(p + 8*q)*64 + lane];
  __syncthreads();                     // reads done before fft128 rewrites lds

  fft128<-1>(v, lds, lane, p);         // v[c*8+t] = b at m2=(2p+c)+16*bitrev3(t)

#pragma unroll
  for (int c = 0; c < 2; c++){
#pragma unroll
    for (int t = 0; t < 8; t++){
      const int m2 = (2*p + c) + 16*bitrev3(t);
      const float2 a = v[c*8 + t];
      Az[base + (size_t)m2 * D_CH] = packc(a.x, a.y);
    }
  }
}

// ---------------------------------------------------------------------------
// K3 (fused with old K4): inverse step2 over k1 + bias + output write.
// y[0,t,d] = Re(w)+bias, y[1,t,d] = Im(w)+bias, t = m2 + 128*m1, m1 < 64.
// ---------------------------------------------------------------------------
__global__ __launch_bounds__(512, 4)
void k3_inv2(const unsigned* __restrict__ Bz, const float* __restrict__ bias,
             float* __restrict__ out){
  __shared__ float2 lds[8192];
  const int m2 = blockIdx.x, dg = blockIdx.y;
  const int lane = threadIdx.x & 63, p = threadIdx.x >> 6;
  const int d = dg*64 + lane;
  const float bv = bias[d];

  unsigned raw[16];
#pragma unroll
  for (int q = 0; q < 16; q++){
    const int k1 = p + 8*q;
    raw[q] = Bz[((size_t)k1*128 + m2) * D_CH + d];
  }
  float2 v[16];
#pragma unroll
  for (int q = 0; q < 16; q++){
    const int k1 = p + 8*q;
    float sn, cs;
    __sincosf(W_N * (float)(m2 * k1), &sn, &cs);  // e^{+2pi i m2 k1 / 16384}
    const float2 a = upk(raw[q]);
    v[q] = make_float2(a.x*cs - a.y*sn, a.x*sn + a.y*cs);
  }

  fft128<-1>(v, lds, lane, p);         // v[c*8+t] = w[m1=(2p+c)+16*bitrev3(t)]

#pragma unroll
  for (int c = 0; c < 2; c++){
#pragma unroll
    for (int t = 0; t < 8; t += 2){    // bitrev3(t)<4 <=> t even  => m1 < 64
      const int m1 = (2*p + c) + 16*bitrev3(t);
      const int tseq = m2 + 128*m1;
      const float2 a = v[c*8 + t];
      out[(size_t)tseq * D_CH + d]            = a.x + bv;
      out[(size_t)(L_SEQ + tseq) * D_CH + d]  = a.y + bv;
    }
  }
}

// ---------------------------------------------------------------------------
extern "C" void kernel_launch(void* const* d_in, const int* in_sizes, int n_in,
                              void* d_out, int out_size, void* d_ws, size_t ws_size,
                              hipStream_t stream){
  (void)in_sizes; (void)n_in; (void)out_size;
  const float* x    = (const float*)d_in[0];
  const float* h    = (const float*)d_in[1];
  const float* bias = (const float*)d_in[2];
  float* out = (float*)d_out;

  const size_t REGION = (size_t)128 * 128 * D_CH * sizeof(unsigned); // 64 MiB
  unsigned *r1, *r2;
  if (ws_size >= 2 * REGION){
    r1 = (unsigned*)d_ws;                       // A_z -> b
    r2 = (unsigned*)((char*)d_ws + REGION);     // A_h -> Hspec
  } else {
    r1 = (unsigned*)d_out;  // safe: K3 reads a row-class before its stores
    r2 = (unsigned*)d_ws;   // requires ws_size >= 64 MiB
  }

  const dim3 blk(512, 1, 1);
  hipLaunchKernelGGL(k1_step1, dim3(128,16,2), blk, 0, stream, x, h, r1, r2);
  hipLaunchKernelGGL(k2_h,     dim3(128,16,1), blk, 0, stream, r2);
  hipLaunchKernelGGL(k2_z,     dim3(128,16,1), blk, 0, stream, r1, r2);
  hipLaunchKernelGGL(k3_inv2,  dim3(128,16,1), blk, 0, stream, r1, bias, out);
}

// Round 3
// 245.261 us; speedup vs baseline: 1.8094x; 1.0640x over previous
//
#include <hip/hip_runtime.h>

#define D_CH   1024
#define L_SEQ  8192
#define W_N    3.8349519697141029e-4f   /* 2*pi/16384 */
#define W128A  4.90873852123405e-2f     /* 2*pi/128 */

// ---------------- bf16 pack/unpack (manual RNE) --------------------------
__device__ __forceinline__ unsigned f2bf(float v){
  union { float f; unsigned u; } x; x.f = v;
  unsigned r = x.u + 0x7fffu + ((x.u >> 16) & 1u);
  return r >> 16;
}
__device__ __forceinline__ float bf2f(unsigned v){
  union { float f; unsigned u; } x; x.u = v << 16;
  return x.f;
}
__device__ __forceinline__ unsigned packc(float r, float i){
  return f2bf(r) | (f2bf(i) << 16);
}
__device__ __forceinline__ float2 upk(unsigned u){
  return make_float2(bf2f(u & 0xffffu), bf2f(u >> 16));
}

__device__ __host__ constexpr int bitrev4(int j){
  return ((j&1)<<3)|((j&2)<<1)|((j&4)>>1)|((j&8)>>3);
}
__device__ __host__ constexpr int bitrev3(int j){
  return ((j&1)<<2)|(j&2)|((j&4)>>2);
}

// 16-pt DIF DFT, natural in; slot j holds X[bitrev4(j)].
template<int SGN>
__device__ __forceinline__ void dft16(float2* x){
  const float TC[8] = {1.f, 0.9238795325f, 0.7071067812f, 0.3826834324f,
                       0.f, -0.3826834324f, -0.7071067812f, -0.9238795325f};
  const float TS[8] = {0.f, -0.3826834324f, -0.7071067812f, -0.9238795325f,
                       -1.f, -0.9238795325f, -0.7071067812f, -0.3826834324f};
#pragma unroll
  for (int len = 16; len >= 2; len >>= 1){
    const int half = len >> 1, tstep = 16 / len;
#pragma unroll
    for (int st = 0; st < 16; st += len){
#pragma unroll
      for (int j = 0; j < half; j++){
        const float wr = TC[j*tstep];
        const float wi = (SGN > 0) ? TS[j*tstep] : -TS[j*tstep];
        const int a = st + j, b = a + half;
        const float ur = x[a].x, ui = x[a].y;
        const float vr = x[b].x, vi = x[b].y;
        x[a].x = ur + vr; x[a].y = ui + vi;
        const float dr = ur - vr, di = ui - vi;
        x[b].x = dr*wr - di*wi;
        x[b].y = dr*wi + di*wr;
      }
    }
  }
}

// 8-pt DIF DFT, natural in; slot j holds X[bitrev3(j)].
template<int SGN>
__device__ __forceinline__ void dft8(float2* x){
  const float TC[4] = {1.f, 0.7071067812f, 0.f, -0.7071067812f};
  const float TS[4] = {0.f, -0.7071067812f, -1.f, -0.7071067812f};
#pragma unroll
  for (int len = 8; len >= 2; len >>= 1){
    const int half = len >> 1, tstep = 8 / len;
#pragma unroll
    for (int st = 0; st < 8; st += len){
#pragma unroll
      for (int j = 0; j < half; j++){
        const float wr = TC[j*tstep];
        const float wi = (SGN > 0) ? TS[j*tstep] : -TS[j*tstep];
        const int a = st + j, b = a + half;
        const float ur = x[a].x, ui = x[a].y;
        const float vr = x[b].x, vi = x[b].y;
        x[a].x = ur + vr; x[a].y = ui + vi;
        const float dr = ur - vr, di = ui - vi;
        x[b].x = dr*wr - di*wi;
        x[b].y = dr*wi + di*wr;
      }
    }
  }
}

// 128-pt DFT across 8 p-threads (p = tid>>6) x 64 channels (lane).
// Entry: v[q] = f[p + 8q]. Exit: v[c*8+t] = F[(2p+c) + 16*bitrev3(t)].
// Parity-split transpose: only 32 KiB LDS (float2[4096]); 3 internal
// barriers. Caller must __syncthreads() before reusing lds afterwards.
template<int SGN>
__device__ __forceinline__ void fft128(float2* v, float2* lds, int lane, int p){
  dft16<SGN>(v);                         // slot -> s = bitrev4(slot)
  // ---- phase 0: slots 0..7 (s = 2r even, r = bitrev3(slot)) ----
#pragma unroll
  for (int slot = 0; slot < 8; slot++){
    const int r = bitrev3(slot);
    float sn, cs;
    __sincosf(-(float)SGN * W128A * (float)(p*(2*r)), &sn, &cs);
    const float2 a = v[slot];
    lds[(p*8 + r)*64 + lane] = make_float2(a.x*cs - a.y*sn, a.x*sn + a.y*cs);
  }
  __syncthreads();
  float2 t8[8];
#pragma unroll
  for (int pp = 0; pp < 8; pp++) t8[pp] = lds[(pp*8 + p)*64 + lane]; // s=2p
  dft8<SGN>(t8);
#pragma unroll
  for (int t = 0; t < 8; t++) v[t] = t8[t];
  __syncthreads();                       // reads done before phase-1 stores
  // ---- phase 1: slots 8..15 (s = 2r+1 odd) ----
#pragma unroll
  for (int slot = 8; slot < 16; slot++){
    const int r = bitrev3(slot - 8);
    float sn, cs;
    __sincosf(-(float)SGN * W128A * (float)(p*(2*r+1)), &sn, &cs);
    const float2 a = v[slot];
    lds[(p*8 + r)*64 + lane] = make_float2(a.x*cs - a.y*sn, a.x*sn + a.y*cs);
  }
  __syncthreads();
#pragma unroll
  for (int pp = 0; pp < 8; pp++) t8[pp] = lds[(pp*8 + p)*64 + lane]; // s=2p+1
  dft8<SGN>(t8);
#pragma unroll
  for (int t = 0; t < 8; t++) v[8 + t] = t8[t];
}

// ---------------------------------------------------------------------------
// K1: forward step1 over n1 (64 nonzero of 128, zero-padded).
// A[k1,n2] = w16384^{k1 n2} * DFT128_{n1}(z[n2+128 n1]).
// mode 0: z = x[0] + i x[1]; mode 1: h.
// ---------------------------------------------------------------------------
__global__ __launch_bounds__(512, 8)
void k1_step1(const float* __restrict__ x, const float* __restrict__ h,
              unsigned* __restrict__ Az, unsigned* __restrict__ Ah){
  __shared__ float2 lds[4096];
  const int n2 = blockIdx.x, dg = blockIdx.y, mode = blockIdx.z;
  const int lane = threadIdx.x & 63, p = threadIdx.x >> 6;
  const int d = dg*64 + lane;

  float2 v[16];
  if (mode == 0){
    const float* x0 = x;
    const float* x1 = x + (size_t)L_SEQ * D_CH;
#pragma unroll
    for (int q = 0; q < 8; q++){
      const size_t off = (size_t)(n2 + 128*(p + 8*q)) * D_CH + d;
      v[q] = make_float2(x0[off], x1[off]);
    }
  } else {
#pragma unroll
    for (int q = 0; q < 8; q++){
      const size_t off = (size_t)(n2 + 128*(p + 8*q)) * D_CH + d;
      v[q] = make_float2(h[off], 0.0f);
    }
  }
#pragma unroll
  for (int q = 8; q < 16; q++) v[q] = make_float2(0.f, 0.f);

  fft128<1>(v, lds, lane, p);

  unsigned* __restrict__ A = mode ? Ah : Az;
#pragma unroll
  for (int c = 0; c < 2; c++){
#pragma unroll
    for (int t = 0; t < 8; t++){
      const int k1v = (2*p + c) + 16*bitrev3(t);
      float sn, cs;
      __sincosf(-W_N * (float)(k1v * n2), &sn, &cs);
      const float2 a = v[c*8 + t];
      A[((size_t)k1v*128 + n2)*D_CH + d] =
        packc(a.x*cs - a.y*sn, a.x*sn + a.y*cs);
    }
  }
}

// ---------------------------------------------------------------------------
// K2 (fused): forward step2 for h (in-register Hspec, never stored) +
// forward step2 for z + pointwise Z*H/16384 + inverse DFT over k2,
// in place on A_z: result b[k1,m2] stored at natural m2.
// Thread p's z-spectrum order (2p+c)+16*bitrev3(t) matches its own
// h-spectrum order exactly -> elementwise multiply, no reshuffle.
// ---------------------------------------------------------------------------
__global__ __launch_bounds__(512, 4)
void k2_zh(unsigned* __restrict__ Az, const unsigned* __restrict__ Ah){
  __shared__ float2 lds[4096];
  const int k1 = blockIdx.x, dg = blockIdx.y;
  const int lane = threadIdx.x & 63, p = threadIdx.x >> 6;
  const int d = dg*64 + lane;
  const size_t base = (size_t)k1 * 128 * D_CH + d;

  // issue all independent loads up front (MLP)
  unsigned ha[16], za[16];
#pragma unroll
  for (int q = 0; q < 16; q++)
    ha[q] = Ah[base + (size_t)(p + 8*q) * D_CH];
#pragma unroll
  for (int q = 0; q < 16; q++)
    za[q] = Az[base + (size_t)(p + 8*q) * D_CH];

  // ---- H: forward 128-pt over n2, keep spectrum packed in regs ----
  float2 v[16];
#pragma unroll
  for (int q = 0; q < 16; q++) v[q] = upk(ha[q]);
  fft128<1>(v, lds, lane, p);
  unsigned hs[16];
  const float sc = 1.0f / 16384.0f;      // fold ifft scale into Hspec
#pragma unroll
  for (int i = 0; i < 16; i++) hs[i] = packc(v[i].x * sc, v[i].y * sc);
  __syncthreads();                       // lds reads done before z-fft stores

  // ---- Z: forward 128-pt over n2 ----
#pragma unroll
  for (int q = 0; q < 16; q++) v[q] = upk(za[q]);
  fft128<1>(v, lds, lane, p);

  // ---- pointwise multiply (orders match) ----
#pragma unroll
  for (int i = 0; i < 16; i++){
    const float2 hv = upk(hs[i]);
    const float zr = v[i].x, zi = v[i].y;
    v[i] = make_float2(zr*hv.x - zi*hv.y, zr*hv.y + zi*hv.x);
  }

  // ---- redistribute to natural k2 order: v[q] = Y[p+8q] ----
  __syncthreads();                       // protect fft128's lds reads
  float2 w[16];
  // phase A: k2 < 64  (t even)
#pragma unroll
  for (int c = 0; c < 2; c++)
#pragma unroll
    for (int t = 0; t < 8; t += 2){
      const int k2 = (2*p + c) + 16*bitrev3(t);
      lds[k2*64 + lane] = v[c*8 + t];
    }
  __syncthreads();
#pragma unroll
  for (int q = 0; q < 8; q++) w[q] = lds[(p + 8*q)*64 + lane];
  __syncthreads();
  // phase B: k2 >= 64 (t odd)
#pragma unroll
  for (int c = 0; c < 2; c++)
#pragma unroll
    for (int t = 1; t < 8; t += 2){
      const int k2 = (2*p + c) + 16*bitrev3(t) - 64;
      lds[k2*64 + lane] = v[c*8 + t];
    }
  __syncthreads();
#pragma unroll
  for (int q = 0; q < 8; q++) w[8 + q] = lds[(p + 8*q)*64 + lane];
  __syncthreads();                       // reads done before inverse stores
#pragma unroll
  for (int q = 0; q < 16; q++) v[q] = w[q];

  // ---- inverse 128-pt over k2 ----
  fft128<-1>(v, lds, lane, p);           // v[c*8+t] = b at m2=(2p+c)+16*bitrev3(t)

#pragma unroll
  for (int c = 0; c < 2; c++){
#pragma unroll
    for (int t = 0; t < 8; t++){
      const int m2 = (2*p + c) + 16*bitrev3(t);
      const float2 a = v[c*8 + t];
      Az[base + (size_t)m2 * D_CH] = packc(a.x, a.y);
    }
  }
}

// ---------------------------------------------------------------------------
// K3: inverse step2 over k1 + bias + output write.
// y[0,t,d] = Re(w)+bias, y[1,t,d] = Im(w)+bias, t = m2 + 128*m1, m1 < 64.
// ---------------------------------------------------------------------------
__global__ __launch_bounds__(512, 6)
void k3_inv2(const unsigned* __restrict__ Bz, const float* __restrict__ bias,
             float* __restrict__ out){
  __shared__ float2 lds[4096];
  const int m2 = blockIdx.x, dg = blockIdx.y;
  const int lane = threadIdx.x & 63, p = threadIdx.x >> 6;
  const int d = dg*64 + lane;
  const float bv = bias[d];

  unsigned raw[16];
#pragma unroll
  for (int q = 0; q < 16; q++){
    const int k1 = p + 8*q;
    raw[q] = Bz[((size_t)k1*128 + m2) * D_CH + d];
  }
  float2 v[16];
#pragma unroll
  for (int q = 0; q < 16; q++){
    const int k1 = p + 8*q;
    float sn, cs;
    __sincosf(W_N * (float)(m2 * k1), &sn, &cs);  // e^{+2pi i m2 k1 / 16384}
    const float2 a = upk(raw[q]);
    v[q] = make_float2(a.x*cs - a.y*sn, a.x*sn + a.y*cs);
  }

  fft128<-1>(v, lds, lane, p);           // v[c*8+t] = w[m1=(2p+c)+16*bitrev3(t)]

#pragma unroll
  for (int c = 0; c < 2; c++){
#pragma unroll
    for (int t = 0; t < 8; t += 2){      // t even <=> bitrev3(t)<4 <=> m1 < 64
      const int m1 = (2*p + c) + 16*bitrev3(t);
      const int tseq = m2 + 128*m1;
      const float2 a = v[c*8 + t];
      out[(size_t)tseq * D_CH + d]            = a.x + bv;
      out[(size_t)(L_SEQ + tseq) * D_CH + d]  = a.y + bv;
    }
  }
}

// ---------------------------------------------------------------------------
extern "C" void kernel_launch(void* const* d_in, const int* in_sizes, int n_in,
                              void* d_out, int out_size, void* d_ws, size_t ws_size,
                              hipStream_t stream){
  (void)in_sizes; (void)n_in; (void)out_size;
  const float* x    = (const float*)d_in[0];
  const float* h    = (const float*)d_in[1];
  const float* bias = (const float*)d_in[2];
  float* out = (float*)d_out;

  const size_t REGION = (size_t)128 * 128 * D_CH * sizeof(unsigned); // 64 MiB
  unsigned *r1, *r2;
  if (ws_size >= 2 * REGION){
    r1 = (unsigned*)d_ws;                       // A_z -> b
    r2 = (unsigned*)((char*)d_ws + REGION);     // A_h
  } else {
    r1 = (unsigned*)d_out;  // safe: K3 reads each r1 cell before its stores
    r2 = (unsigned*)d_ws;   // requires ws_size >= 64 MiB
  }

  const dim3 blk(512, 1, 1);
  hipLaunchKernelGGL(k1_step1, dim3(128,16,2), blk, 0, stream, x, h, r1, r2);
  hipLaunchKernelGGL(k2_zh,    dim3(128,16,1), blk, 0, stream, r1, r2);
  hipLaunchKernelGGL(k3_inv2,  dim3(128,16,1), blk, 0, stream, r1, bias, out);
}